// Round 3
// baseline (16204.509 us; speedup 1.0000x reference)
//
#include <hip/hip_runtime.h>
#include <hip/hip_bf16.h>

typedef unsigned short ushort_t;

#define N_NODES 50000
#define N_EDGES 100000
#define N_GRAPH 2000
#define DIM     300
#define DIM2    600
#define NLAYER  5
#define NTASK   10
#define D4      75   // DIM/4

static __device__ __forceinline__ float bf2f(ushort_t b) {
    unsigned int u = ((unsigned int)b) << 16;
    float f;
    __builtin_memcpy(&f, &u, 4);
    return f;
}
static __device__ __forceinline__ ushort_t f2bf(float f) {
    unsigned int u;
    __builtin_memcpy(&u, &f, 4);
    unsigned int lsb = (u >> 16) & 1u;
    u += 0x7fffu + lsb;
    return (ushort_t)(u >> 16);
}

static __device__ __forceinline__ float ldf(const float* p) { return *p; }
static __device__ __forceinline__ float ldf(const ushort_t* p) { return bf2f(*p); }

static __device__ __forceinline__ void stf(float* p, float v) { *p = v; }
static __device__ __forceinline__ void stf(ushort_t* p, float v) { *p = f2bf(v); }

// h[n,d] = xemb1[x[n,0],d] + xemb2[x[n,1],d]   (fp32 embeddings)
__global__ void k_embed_init(const int* __restrict__ x,
                             const float* __restrict__ xe1,
                             const float* __restrict__ xe2,
                             float* __restrict__ h) {
    int tid = blockIdx.x * blockDim.x + threadIdx.x;
    if (tid >= N_NODES * D4) return;
    int node = tid / D4;
    int d0 = (tid % D4) * 4;
    int i0 = x[node * 2 + 0];
    int i1 = x[node * 2 + 1];
    float4 a = *(const float4*)(xe1 + (size_t)i0 * DIM + d0);
    float4 b = *(const float4*)(xe2 + (size_t)i1 * DIM + d0);
    float4 o;
    o.x = a.x + b.x; o.y = a.y + b.y; o.z = a.z + b.z; o.w = a.w + b.w;
    *(float4*)(h + (size_t)node * DIM + d0) = o;
}

// agg[n,:] = h[n,:] + selfloop_emb   (selfloop: eemb1[l][4] + eemb2[l][0])
__global__ void k_agg_init(const float* __restrict__ h,
                           const float* __restrict__ ee1sl,
                           const float* __restrict__ ee2sl,
                           float* __restrict__ agg) {
    int tid = blockIdx.x * blockDim.x + threadIdx.x;
    if (tid >= N_NODES * D4) return;
    int node = tid / D4;
    int d0 = (tid % D4) * 4;
    float4 hv = *(const float4*)(h + (size_t)node * DIM + d0);
    float4 e1 = *(const float4*)(ee1sl + d0);
    float4 e2 = *(const float4*)(ee2sl + d0);
    float4 o;
    o.x = hv.x + e1.x + e2.x;
    o.y = hv.y + e1.y + e2.y;
    o.z = hv.z + e1.z + e2.z;
    o.w = hv.w + e1.w + e2.w;
    *(float4*)(agg + (size_t)node * DIM + d0) = o;
}

// for each edge e: agg[dst[e],:] += h[src[e],:] + eemb1[l][ea0] + eemb2[l][ea1]
__global__ void k_edge_scatter(const int* __restrict__ ei,
                               const int* __restrict__ ea,
                               const float* __restrict__ h,
                               const float* __restrict__ ee1,
                               const float* __restrict__ ee2,
                               float* __restrict__ agg) {
    int tid = blockIdx.x * blockDim.x + threadIdx.x;
    if (tid >= N_EDGES * D4) return;
    int e = tid / D4;
    int d0 = (tid % D4) * 4;
    int src = ei[e];
    int dst = ei[N_EDGES + e];
    int a0 = ea[2 * e + 0];
    int a1 = ea[2 * e + 1];
    float4 hv = *(const float4*)(h + (size_t)src * DIM + d0);
    float4 e1 = *(const float4*)(ee1 + (size_t)a0 * DIM + d0);
    float4 e2 = *(const float4*)(ee2 + (size_t)a1 * DIM + d0);
    float* dp = agg + (size_t)dst * DIM + d0;
    atomicAdd(dp + 0, hv.x + e1.x + e2.x);
    atomicAdd(dp + 1, hv.y + e1.y + e2.y);
    atomicAdd(dp + 2, hv.z + e1.z + e2.z);
    atomicAdd(dp + 3, hv.w + e1.w + e2.w);
}

// C[M,N] = act(A[M,K] @ B[K,N] + bias[N]); A fp32 or bf16, B/bias fp32, C fp32 or bf16
template <bool RELU, typename AT, typename OT>
__global__ __launch_bounds__(256) void k_gemm_bias(const AT* __restrict__ A,
                                                   const float* __restrict__ B,
                                                   const float* __restrict__ bias,
                                                   OT* __restrict__ C,
                                                   int M, int N, int K) {
    const int BM = 64, BN = 64, BK = 16;
    __shared__ float As[BK][BM + 1];
    __shared__ float Bs[BK][BN + 1];
    int m0 = blockIdx.y * BM;
    int n0 = blockIdx.x * BN;
    int t = threadIdx.x;
    int tx = t & 15;   // col group
    int ty = t >> 4;   // row group
    float acc[4][4] = {{0.f}};

    for (int kk = 0; kk < K; kk += BK) {
        // load A tile: id -> k = id&15, m = id>>4 (coalesced along k)
#pragma unroll
        for (int it = 0; it < 4; ++it) {
            int id = t + it * 256;
            int k = id & 15;
            int m = id >> 4;
            int row = m0 + m, col = kk + k;
            float v = 0.f;
            if (row < M && col < K) v = ldf(&A[(size_t)row * K + col]);
            As[k][m] = v;
        }
        // load B tile: id -> n = id&63, k = id>>6 (coalesced along n)
#pragma unroll
        for (int it = 0; it < 4; ++it) {
            int id = t + it * 256;
            int n = id & 63;
            int k = id >> 6;
            int row = kk + k, col = n0 + n;
            float v = 0.f;
            if (row < K && col < N) v = B[(size_t)row * N + col];
            Bs[k][n] = v;
        }
        __syncthreads();
#pragma unroll
        for (int k = 0; k < BK; ++k) {
            float a[4], b[4];
#pragma unroll
            for (int i = 0; i < 4; ++i) a[i] = As[k][ty * 4 + i];
#pragma unroll
            for (int j = 0; j < 4; ++j) b[j] = Bs[k][tx * 4 + j];
#pragma unroll
            for (int i = 0; i < 4; ++i)
#pragma unroll
                for (int j = 0; j < 4; ++j) acc[i][j] += a[i] * b[j];
        }
        __syncthreads();
    }

#pragma unroll
    for (int i = 0; i < 4; ++i) {
        int row = m0 + ty * 4 + i;
        if (row >= M) continue;
#pragma unroll
        for (int j = 0; j < 4; ++j) {
            int col = n0 + tx * 4 + j;
            if (col >= N) continue;
            float v = acc[i][j] + bias[col];
            if (RELU) v = fmaxf(v, 0.f);
            stf(&C[(size_t)row * N + col], v);
        }
    }
}

// partial per-column sums of h2 (N rows x DIM cols) into double accumulators
__global__ void k_bn_reduce(const float* __restrict__ h2,
                            double* __restrict__ sum,
                            double* __restrict__ sumsq) {
    const int ROWS = 128;
    int r0 = blockIdx.x * ROWS;
    int rend = r0 + ROWS;
    if (rend > N_NODES) rend = N_NODES;
    for (int d = threadIdx.x; d < DIM; d += 256) {
        float s = 0.f, q = 0.f;
        for (int r = r0; r < rend; ++r) {
            float v = h2[(size_t)r * DIM + d];
            s += v;
            q += v * v;
        }
        atomicAdd(&sum[d], (double)s);
        atomicAdd(&sumsq[d], (double)q);
    }
}

__global__ void k_bn_finalize(const double* __restrict__ sum,
                              const double* __restrict__ sumsq,
                              float* __restrict__ mean,
                              float* __restrict__ rstd) {
    int d = threadIdx.x;
    if (d >= DIM) return;
    double mu = sum[d] / (double)N_NODES;
    double var = sumsq[d] / (double)N_NODES - mu * mu;
    if (var < 0.0) var = 0.0;
    mean[d] = (float)mu;
    rstd[d] = (float)(1.0 / sqrt(var + 1e-5));
}

template <bool RELU, bool WOUT>
__global__ void k_bn_apply(const float* __restrict__ h2,
                           const float* __restrict__ mean,
                           const float* __restrict__ rstd,
                           const float* __restrict__ gamma,
                           const float* __restrict__ beta,
                           float* __restrict__ h,
                           float* __restrict__ nodeout) {
    int tid = blockIdx.x * blockDim.x + threadIdx.x;
    if (tid >= N_NODES * D4) return;
    int node = tid / D4;
    int d0 = (tid % D4) * 4;
    float4 v = *(const float4*)(h2 + (size_t)node * DIM + d0);
    float o[4] = {v.x, v.y, v.z, v.w};
    float4 r;
    float* rp = &r.x;
#pragma unroll
    for (int i = 0; i < 4; ++i) {
        int d = d0 + i;
        float u = (o[i] - mean[d]) * rstd[d] * gamma[d] + beta[d];
        if (RELU) u = fmaxf(u, 0.f);
        rp[i] = u;
    }
    *(float4*)(h + (size_t)node * DIM + d0) = r;
    if (WOUT) *(float4*)(nodeout + (size_t)node * DIM + d0) = r;
}

__global__ void k_pool_cnt(const int* __restrict__ batch, float* __restrict__ cnt) {
    int tid = blockIdx.x * blockDim.x + threadIdx.x;
    if (tid >= N_NODES) return;
    atomicAdd(&cnt[batch[tid]], 1.0f);
}

__global__ void k_pool_sum(const float* __restrict__ h,
                           const int* __restrict__ batch,
                           float* __restrict__ pool) {
    int tid = blockIdx.x * blockDim.x + threadIdx.x;
    if (tid >= N_NODES * D4) return;
    int node = tid / D4;
    int d0 = (tid % D4) * 4;
    int g = batch[node];
    float4 v = *(const float4*)(h + (size_t)node * DIM + d0);
    float* dp = pool + (size_t)g * DIM + d0;
    atomicAdd(dp + 0, v.x);
    atomicAdd(dp + 1, v.y);
    atomicAdd(dp + 2, v.z);
    atomicAdd(dp + 3, v.w);
}

__global__ void k_pool_div(float* __restrict__ pool,
                           const float* __restrict__ cnt,
                           float* __restrict__ gout) {
    int tid = blockIdx.x * blockDim.x + threadIdx.x;
    if (tid >= N_GRAPH * D4) return;
    int g = tid / D4;
    int d0 = (tid % D4) * 4;
    float c = fmaxf(cnt[g], 1.0f);
    float* pp = pool + (size_t)g * DIM + d0;
    float4 r;
    r.x = pp[0] / c; r.y = pp[1] / c; r.z = pp[2] / c; r.w = pp[3] / c;
    *(float4*)pp = r;
    *(float4*)(gout + (size_t)g * DIM + d0) = r;
}

__global__ void k_pred(const float* __restrict__ pool,
                       const float* __restrict__ predW,
                       const float* __restrict__ predb,
                       float* __restrict__ out) {
    int tid = blockIdx.x * blockDim.x + threadIdx.x;
    if (tid >= N_GRAPH * NTASK) return;
    int g = tid / NTASK;
    int t = tid % NTASK;
    float s = predb[t];
    const float* pr = pool + (size_t)g * DIM;
    for (int k = 0; k < DIM; ++k) s += pr[k] * predW[k * NTASK + t];
    out[(size_t)g * NTASK + t] = s;
}

static inline int cdiv(long long a, long long b) { return (int)((a + b - 1) / b); }

extern "C" void kernel_launch(void* const* d_in, const int* in_sizes, int n_in,
                              void* d_out, int out_size, void* d_ws, size_t ws_size,
                              hipStream_t stream) {
    // inputs per setup_inputs() order; int tensors int32, float tensors fp32
    const int* x    = (const int*)d_in[0];
    const int* ei   = (const int*)d_in[1];
    const int* ea   = (const int*)d_in[2];
    const int* bat  = (const int*)d_in[3];
    const int* x1   = (const int*)d_in[4];
    const int* ei1  = (const int*)d_in[5];
    const int* ea1  = (const int*)d_in[6];
    const int* bat1 = (const int*)d_in[7];
    const float* xemb1 = (const float*)d_in[8];
    const float* xemb2 = (const float*)d_in[9];
    const float* eemb1 = (const float*)d_in[10];
    const float* eemb2 = (const float*)d_in[11];
    const float* W1    = (const float*)d_in[12];
    const float* b1    = (const float*)d_in[13];
    const float* W2    = (const float*)d_in[14];
    const float* b2    = (const float*)d_in[15];
    const float* gamma = (const float*)d_in[16];
    const float* beta  = (const float*)d_in[17];
    const float* predW = (const float*)d_in[18];
    const float* predb = (const float*)d_in[19];
    float* out = (float*)d_out;  // reference outputs are float32

    // workspace layout (256B aligned blocks), ~182.4 MB total
    char* ws = (char*)d_ws;
    size_t off = 0;
    auto take = [&](size_t bytes) -> char* {
        char* p = ws + off;
        off += (bytes + 255) & ~(size_t)255;
        return p;
    };
    float* h      = (float*)take((size_t)N_NODES * DIM * 4);
    float* agg    = (float*)take((size_t)N_NODES * DIM * 4);  // also h2 (aliased)
    ushort_t* y   = (ushort_t*)take((size_t)N_NODES * DIM2 * 2);
    float* pool   = (float*)take((size_t)N_GRAPH * DIM * 4 + (size_t)N_GRAPH * 4);
    float* cnt    = pool + (size_t)N_GRAPH * DIM;
    double* bnsum = (double*)take(DIM * 8 * 2);
    double* bnsq  = bnsum + DIM;
    float* bnmean = (float*)take(DIM * 4 * 2);
    float* bnrstd = bnmean + DIM;
    float* h2 = agg;
    (void)ws_size; (void)in_sizes; (void)n_in; (void)out_size;

    const int TB = 256;
    const int gN75 = cdiv((long long)N_NODES * D4, TB);
    const int gE75 = cdiv((long long)N_EDGES * D4, TB);

    auto run_gnn = [&](const int* xp, const int* eip, const int* eap, const int* batp,
                       float* out_pred, float* out_graph, float* out_node) {
        k_embed_init<<<gN75, TB, 0, stream>>>(xp, xemb1, xemb2, h);
        for (int l = 0; l < NLAYER; ++l) {
            const float* ee1l = eemb1 + (size_t)l * 6 * DIM;
            const float* ee2l = eemb2 + (size_t)l * 3 * DIM;
            k_agg_init<<<gN75, TB, 0, stream>>>(h, ee1l + 4 * DIM, ee2l, agg);
            k_edge_scatter<<<gE75, TB, 0, stream>>>(eip, eap, h, ee1l, ee2l, agg);
            k_gemm_bias<true, float, ushort_t>
                <<<dim3(cdiv(DIM2, 64), cdiv(N_NODES, 64)), TB, 0, stream>>>(
                    agg, W1 + (size_t)l * DIM * DIM2, b1 + (size_t)l * DIM2, y,
                    N_NODES, DIM2, DIM);
            k_gemm_bias<false, ushort_t, float>
                <<<dim3(cdiv(DIM, 64), cdiv(N_NODES, 64)), TB, 0, stream>>>(
                    y, W2 + (size_t)l * DIM2 * DIM, b2 + (size_t)l * DIM, h2,
                    N_NODES, DIM, DIM2);
            hipMemsetAsync(bnsum, 0, DIM * 8 * 2, stream);
            k_bn_reduce<<<cdiv(N_NODES, 128), TB, 0, stream>>>(h2, bnsum, bnsq);
            k_bn_finalize<<<1, 512, 0, stream>>>(bnsum, bnsq, bnmean, bnrstd);
            if (l < NLAYER - 1)
                k_bn_apply<true, false><<<gN75, TB, 0, stream>>>(
                    h2, bnmean, bnrstd, gamma + (size_t)l * DIM, beta + (size_t)l * DIM, h, nullptr);
            else
                k_bn_apply<false, true><<<gN75, TB, 0, stream>>>(
                    h2, bnmean, bnrstd, gamma + (size_t)l * DIM, beta + (size_t)l * DIM, h, out_node);
        }
        hipMemsetAsync(pool, 0, (size_t)N_GRAPH * DIM * 4 + (size_t)N_GRAPH * 4, stream);
        k_pool_cnt<<<cdiv(N_NODES, TB), TB, 0, stream>>>(batp, cnt);
        k_pool_sum<<<gN75, TB, 0, stream>>>(h, batp, pool);
        k_pool_div<<<cdiv((long long)N_GRAPH * D4, TB), TB, 0, stream>>>(pool, cnt, out_graph);
        k_pred<<<cdiv((long long)N_GRAPH * NTASK, TB), TB, 0, stream>>>(pool, predW, predb, out_pred);
    };

    const size_t GT = (size_t)N_GRAPH * NTASK;       // 20000
    const size_t GD = (size_t)N_GRAPH * DIM;         // 600000
    const size_t ND = (size_t)N_NODES * DIM;         // 15000000
    run_gnn(x, ei, ea, bat, out, out + GT, out + GT + GD);
    run_gnn(x1, ei1, ea1, bat1, out + GT + GD + ND, out + 2 * GT + GD + ND, out + 2 * GT + 2 * GD + ND);
}

// Round 4
// 8294.358 us; speedup vs baseline: 1.9537x; 1.9537x over previous
//
#include <hip/hip_runtime.h>
#include <hip/hip_bf16.h>

typedef unsigned short ushort_t;
typedef short v8s __attribute__((ext_vector_type(8)));
typedef unsigned short v8u __attribute__((ext_vector_type(8)));
typedef float v4f __attribute__((ext_vector_type(4)));

#define N_NODES 50000
#define N_EDGES 100000
#define N_GRAPH 2000
#define DIM     300
#define DIM2    600
#define NLAYER  5
#define NTASK   10
#define D4      75   // DIM/4

// GEMM1: K=300 -> Ksteps=10, KB=40; N=600 -> NT=5 (Npad 640)
// GEMM2: K=600 -> Ksteps=19, KB=76; N=300 -> NT=3 (Npad 384)
#define KB1 40
#define NT1 5
#define KB2 76
#define NT2 3
#define MT_TILES 391  // ceil(50000/128)

static __device__ __forceinline__ float bf2f(ushort_t b) {
    unsigned int u = ((unsigned int)b) << 16;
    float f;
    __builtin_memcpy(&f, &u, 4);
    return f;
}
static __device__ __forceinline__ ushort_t f2bf(float f) {
    unsigned int u;
    __builtin_memcpy(&u, &f, 4);
    unsigned int lsb = (u >> 16) & 1u;
    u += 0x7fffu + lsb;
    return (ushort_t)(u >> 16);
}
// split fp32 into truncated-hi bf16 + residual-lo bf16 (hi + lo ~= f to ~2^-17)
static __device__ __forceinline__ void split2(float f, ushort_t& h, ushort_t& l) {
    unsigned int u;
    __builtin_memcpy(&u, &f, 4);
    h = (ushort_t)(u >> 16);
    unsigned int um = u & 0xFFFF0000u;
    float hf;
    __builtin_memcpy(&hf, &um, 4);
    float lf = f - hf;
    unsigned int ul;
    __builtin_memcpy(&ul, &lf, 4);
    l = (ushort_t)(ul >> 16);
}

// h[n,d] = xemb1[x[n,0],d] + xemb2[x[n,1],d]   (fp32 embeddings)
__global__ void k_embed_init(const int* __restrict__ x,
                             const float* __restrict__ xe1,
                             const float* __restrict__ xe2,
                             float* __restrict__ h) {
    int tid = blockIdx.x * blockDim.x + threadIdx.x;
    if (tid >= N_NODES * D4) return;
    int node = tid / D4;
    int d0 = (tid % D4) * 4;
    int i0 = x[node * 2 + 0];
    int i1 = x[node * 2 + 1];
    float4 a = *(const float4*)(xe1 + (size_t)i0 * DIM + d0);
    float4 b = *(const float4*)(xe2 + (size_t)i1 * DIM + d0);
    float4 o;
    o.x = a.x + b.x; o.y = a.y + b.y; o.z = a.z + b.z; o.w = a.w + b.w;
    *(float4*)(h + (size_t)node * DIM + d0) = o;
}

// agg[n,:] = h[n,:] + selfloop_emb
__global__ void k_agg_init(const float* __restrict__ h,
                           const float* __restrict__ ee1sl,
                           const float* __restrict__ ee2sl,
                           float* __restrict__ agg) {
    int tid = blockIdx.x * blockDim.x + threadIdx.x;
    if (tid >= N_NODES * D4) return;
    int node = tid / D4;
    int d0 = (tid % D4) * 4;
    float4 hv = *(const float4*)(h + (size_t)node * DIM + d0);
    float4 e1 = *(const float4*)(ee1sl + d0);
    float4 e2 = *(const float4*)(ee2sl + d0);
    float4 o;
    o.x = hv.x + e1.x + e2.x;
    o.y = hv.y + e1.y + e2.y;
    o.z = hv.z + e1.z + e2.z;
    o.w = hv.w + e1.w + e2.w;
    *(float4*)(agg + (size_t)node * DIM + d0) = o;
}

// agg[dst[e],:] += h[src[e],:] + eemb1[l][ea0] + eemb2[l][ea1]
__global__ void k_edge_scatter(const int* __restrict__ ei,
                               const int* __restrict__ ea,
                               const float* __restrict__ h,
                               const float* __restrict__ ee1,
                               const float* __restrict__ ee2,
                               float* __restrict__ agg) {
    int tid = blockIdx.x * blockDim.x + threadIdx.x;
    if (tid >= N_EDGES * D4) return;
    int e = tid / D4;
    int d0 = (tid % D4) * 4;
    int src = ei[e];
    int dst = ei[N_EDGES + e];
    int a0 = ea[2 * e + 0];
    int a1 = ea[2 * e + 1];
    float4 hv = *(const float4*)(h + (size_t)src * DIM + d0);
    float4 e1 = *(const float4*)(ee1 + (size_t)a0 * DIM + d0);
    float4 e2 = *(const float4*)(ee2 + (size_t)a1 * DIM + d0);
    float* dp = agg + (size_t)dst * DIM + d0;
    atomicAdd(dp + 0, hv.x + e1.x + e2.x);
    atomicAdd(dp + 1, hv.y + e1.y + e2.y);
    atomicAdd(dp + 2, hv.z + e1.z + e2.z);
    atomicAdd(dp + 3, hv.w + e1.w + e2.w);
}

// Pack weights W [L][K][N] fp32 -> hi/lo bf16 planes in tiled layout
// [l][nt][kb][n(128)][j(8)], zero-padded beyond K/N.
__global__ void k_pack_w(const float* __restrict__ W,
                         ushort_t* __restrict__ hi,
                         ushort_t* __restrict__ lo,
                         int K, int N, int KBv, int NTv, int total) {
    int idx = blockIdx.x * blockDim.x + threadIdx.x;
    if (idx >= total) return;
    int j = idx & 7;
    int n = (idx >> 3) & 127;
    int tmp = idx >> 10;
    int kb = tmp % KBv; tmp /= KBv;
    int nt = tmp % NTv;
    int l = tmp / NTv;
    int k = kb * 8 + j;
    int ng = nt * 128 + n;
    float v = 0.f;
    if (k < K && ng < N) v = W[((size_t)l * K + k) * N + ng];
    ushort_t h, lw;
    split2(v, h, lw);
    hi[idx] = h;
    lo[idx] = lw;
}

// MFMA split-precision GEMM: C[M,N] = act(A[M,Ka] @ W[Ka,N] + bias)
// A fp32 (SPLITA: on-the-fly hi/lo split) or bf16 (hi only).
// W pre-packed hi/lo planes. Block 256 thr = 2x2 waves, tile 128x128, BK=32.
template <bool RELU, bool SPLITA, typename OT>
__global__ __launch_bounds__(256) void k_gemm_mfma(
        const void* __restrict__ Av,
        const ushort_t* __restrict__ Bhi,
        const ushort_t* __restrict__ Blo,
        const float* __restrict__ bias,
        OT* __restrict__ C,
        int M, int Ka, int N, int Ksteps, int KBv) {
    alignas(16) __shared__ ushort_t sAhi[4096];            // [kb4][m128][j8]
    alignas(16) __shared__ ushort_t sAlo[SPLITA ? 4096 : 16];
    alignas(16) __shared__ ushort_t sBhi[4096];            // [kb4][n128][j8]
    alignas(16) __shared__ ushort_t sBlo[4096];

    const int nt = blockIdx.x;
    const int mt = blockIdx.y;
    const int t = threadIdx.x;

    const int w = t >> 6;
    const int lane = t & 63;
    const int wm = w >> 1;     // wave row (0..1)
    const int wn = w & 1;      // wave col (0..1)
    const int quad = lane >> 4;
    const int lr = lane & 15;

    v4f acc[4][4];
#pragma unroll
    for (int i = 0; i < 4; ++i)
#pragma unroll
        for (int j = 0; j < 4; ++j) acc[i][j] = (v4f){0.f, 0.f, 0.f, 0.f};

    // staging indices
    const int sm = t >> 1;       // row within tile 0..127
    const int shalf = t & 1;     // k-half (16 floats each)
    const size_t srow = (size_t)mt * 128 + sm;
    const bool rv = srow < (size_t)M;

    for (int ks = 0; ks < Ksteps; ++ks) {
        const int kk = ks * 32;
        // ---- stage A ----
        if (SPLITA) {
            const float* ap = (const float*)Av + srow * (size_t)Ka;
#pragma unroll
            for (int c = 0; c < 2; ++c) {
                v8u h8, l8;
#pragma unroll
                for (int q2 = 0; q2 < 2; ++q2) {
                    int ko = shalf * 16 + c * 8 + q2 * 4;
                    float4 v = {0.f, 0.f, 0.f, 0.f};
                    if (rv && (kk + ko) < Ka) v = *(const float4*)(ap + kk + ko);
                    const float* vp = &v.x;
#pragma unroll
                    for (int i = 0; i < 4; ++i) {
                        ushort_t hh, ll;
                        split2(vp[i], hh, ll);
                        h8[q2 * 4 + i] = hh;
                        l8[q2 * 4 + i] = ll;
                    }
                }
                int kb = shalf * 2 + c;
                *(v8u*)&sAhi[kb * 1024 + sm * 8] = h8;
                *(v8u*)&sAlo[kb * 1024 + sm * 8] = l8;
            }
        } else {
            const ushort_t* ap = (const ushort_t*)Av + srow * (size_t)Ka;
#pragma unroll
            for (int c = 0; c < 2; ++c) {
                int ko = shalf * 16 + c * 8;
                v8u v = {0, 0, 0, 0, 0, 0, 0, 0};
                if (rv && (kk + ko) < Ka) v = *(const v8u*)(ap + kk + ko);
                *(v8u*)&sAhi[(shalf * 2 + c) * 1024 + sm * 8] = v;
            }
        }
        // ---- stage B (contiguous copy from packed planes) ----
        {
            const size_t base = ((size_t)nt * KBv + ks * 4) * 1024;
            const ushort_t* bh = Bhi + base;
            const ushort_t* bl = Blo + base;
#pragma unroll
            for (int p = 0; p < 2; ++p) {
                int o = p * 2048 + t * 8;
                *(v8u*)&sBhi[o] = *(const v8u*)(bh + o);
                *(v8u*)&sBlo[o] = *(const v8u*)(bl + o);
            }
        }
        __syncthreads();
        // ---- fragments + MFMA ----
        v8s a_hi[4], a_lo[4], b_hi[4], b_lo[4];
#pragma unroll
        for (int s = 0; s < 4; ++s) {
            a_hi[s] = *(const v8s*)&sAhi[quad * 1024 + (wm * 64 + s * 16 + lr) * 8];
            if (SPLITA)
                a_lo[s] = *(const v8s*)&sAlo[quad * 1024 + (wm * 64 + s * 16 + lr) * 8];
            b_hi[s] = *(const v8s*)&sBhi[quad * 1024 + (wn * 64 + s * 16 + lr) * 8];
            b_lo[s] = *(const v8s*)&sBlo[quad * 1024 + (wn * 64 + s * 16 + lr) * 8];
        }
#pragma unroll
        for (int si = 0; si < 4; ++si) {
#pragma unroll
            for (int sj = 0; sj < 4; ++sj) {
                acc[si][sj] = __builtin_amdgcn_mfma_f32_16x16x32_bf16(
                    a_hi[si], b_hi[sj], acc[si][sj], 0, 0, 0);
                acc[si][sj] = __builtin_amdgcn_mfma_f32_16x16x32_bf16(
                    a_hi[si], b_lo[sj], acc[si][sj], 0, 0, 0);
                if (SPLITA)
                    acc[si][sj] = __builtin_amdgcn_mfma_f32_16x16x32_bf16(
                        a_lo[si], b_hi[sj], acc[si][sj], 0, 0, 0);
            }
        }
        __syncthreads();
    }

    // ---- epilogue: bias + act + store ----
#pragma unroll
    for (int sj = 0; sj < 4; ++sj) {
        int col = nt * 128 + wn * 64 + sj * 16 + lr;
        if (col >= N) continue;
        float bv = bias[col];
#pragma unroll
        for (int si = 0; si < 4; ++si) {
#pragma unroll
            for (int r = 0; r < 4; ++r) {
                size_t row = (size_t)mt * 128 + wm * 64 + si * 16 + quad * 4 + r;
                if (row >= (size_t)M) continue;
                float v = acc[si][sj][r] + bv;
                if (RELU) v = fmaxf(v, 0.f);
                if (sizeof(OT) == 2)
                    ((ushort_t*)C)[row * N + col] = f2bf(v);
                else
                    ((float*)C)[row * N + col] = v;
            }
        }
    }
}

// per-column partial sums of h2 into double accumulators
__global__ void k_bn_reduce(const float* __restrict__ h2,
                            double* __restrict__ sum,
                            double* __restrict__ sumsq) {
    const int ROWS = 128;
    int r0 = blockIdx.x * ROWS;
    int rend = r0 + ROWS;
    if (rend > N_NODES) rend = N_NODES;
    for (int d = threadIdx.x; d < DIM; d += 256) {
        float s = 0.f, q = 0.f;
        for (int r = r0; r < rend; ++r) {
            float v = h2[(size_t)r * DIM + d];
            s += v;
            q += v * v;
        }
        atomicAdd(&sum[d], (double)s);
        atomicAdd(&sumsq[d], (double)q);
    }
}

__global__ void k_bn_finalize(const double* __restrict__ sum,
                              const double* __restrict__ sumsq,
                              float* __restrict__ mean,
                              float* __restrict__ rstd) {
    int d = threadIdx.x;
    if (d >= DIM) return;
    double mu = sum[d] / (double)N_NODES;
    double var = sumsq[d] / (double)N_NODES - mu * mu;
    if (var < 0.0) var = 0.0;
    mean[d] = (float)mu;
    rstd[d] = (float)(1.0 / sqrt(var + 1e-5));
}

template <bool RELU, bool WOUT>
__global__ void k_bn_apply(const float* __restrict__ h2,
                           const float* __restrict__ mean,
                           const float* __restrict__ rstd,
                           const float* __restrict__ gamma,
                           const float* __restrict__ beta,
                           float* __restrict__ h,
                           float* __restrict__ nodeout) {
    int tid = blockIdx.x * blockDim.x + threadIdx.x;
    if (tid >= N_NODES * D4) return;
    int node = tid / D4;
    int d0 = (tid % D4) * 4;
    float4 v = *(const float4*)(h2 + (size_t)node * DIM + d0);
    float o[4] = {v.x, v.y, v.z, v.w};
    float4 r;
    float* rp = &r.x;
#pragma unroll
    for (int i = 0; i < 4; ++i) {
        int d = d0 + i;
        float u = (o[i] - mean[d]) * rstd[d] * gamma[d] + beta[d];
        if (RELU) u = fmaxf(u, 0.f);
        rp[i] = u;
    }
    *(float4*)(h + (size_t)node * DIM + d0) = r;
    if (WOUT) *(float4*)(nodeout + (size_t)node * DIM + d0) = r;
}

__global__ void k_pool_cnt(const int* __restrict__ batch, float* __restrict__ cnt) {
    int tid = blockIdx.x * blockDim.x + threadIdx.x;
    if (tid >= N_NODES) return;
    atomicAdd(&cnt[batch[tid]], 1.0f);
}

__global__ void k_pool_sum(const float* __restrict__ h,
                           const int* __restrict__ batch,
                           float* __restrict__ pool) {
    int tid = blockIdx.x * blockDim.x + threadIdx.x;
    if (tid >= N_NODES * D4) return;
    int node = tid / D4;
    int d0 = (tid % D4) * 4;
    int g = batch[node];
    float4 v = *(const float4*)(h + (size_t)node * DIM + d0);
    float* dp = pool + (size_t)g * DIM + d0;
    atomicAdd(dp + 0, v.x);
    atomicAdd(dp + 1, v.y);
    atomicAdd(dp + 2, v.z);
    atomicAdd(dp + 3, v.w);
}

__global__ void k_pool_div(float* __restrict__ pool,
                           const float* __restrict__ cnt,
                           float* __restrict__ gout) {
    int tid = blockIdx.x * blockDim.x + threadIdx.x;
    if (tid >= N_GRAPH * D4) return;
    int g = tid / D4;
    int d0 = (tid % D4) * 4;
    float c = fmaxf(cnt[g], 1.0f);
    float* pp = pool + (size_t)g * DIM + d0;
    float4 r;
    r.x = pp[0] / c; r.y = pp[1] / c; r.z = pp[2] / c; r.w = pp[3] / c;
    *(float4*)pp = r;
    *(float4*)(gout + (size_t)g * DIM + d0) = r;
}

__global__ void k_pred(const float* __restrict__ pool,
                       const float* __restrict__ predW,
                       const float* __restrict__ predb,
                       float* __restrict__ out) {
    int tid = blockIdx.x * blockDim.x + threadIdx.x;
    if (tid >= N_GRAPH * NTASK) return;
    int g = tid / NTASK;
    int tt = tid % NTASK;
    float s = predb[tt];
    const float* pr = pool + (size_t)g * DIM;
    for (int k = 0; k < DIM; ++k) s += pr[k] * predW[k * NTASK + tt];
    out[(size_t)g * NTASK + tt] = s;
}

static inline int cdiv(long long a, long long b) { return (int)((a + b - 1) / b); }

extern "C" void kernel_launch(void* const* d_in, const int* in_sizes, int n_in,
                              void* d_out, int out_size, void* d_ws, size_t ws_size,
                              hipStream_t stream) {
    const int* x    = (const int*)d_in[0];
    const int* ei   = (const int*)d_in[1];
    const int* ea   = (const int*)d_in[2];
    const int* bat  = (const int*)d_in[3];
    const int* x1   = (const int*)d_in[4];
    const int* ei1  = (const int*)d_in[5];
    const int* ea1  = (const int*)d_in[6];
    const int* bat1 = (const int*)d_in[7];
    const float* xemb1 = (const float*)d_in[8];
    const float* xemb2 = (const float*)d_in[9];
    const float* eemb1 = (const float*)d_in[10];
    const float* eemb2 = (const float*)d_in[11];
    const float* W1    = (const float*)d_in[12];
    const float* b1    = (const float*)d_in[13];
    const float* W2    = (const float*)d_in[14];
    const float* b2    = (const float*)d_in[15];
    const float* gamma = (const float*)d_in[16];
    const float* beta  = (const float*)d_in[17];
    const float* predW = (const float*)d_in[18];
    const float* predb = (const float*)d_in[19];
    float* out = (float*)d_out;  // reference outputs are float32

    // workspace layout (~192 MB)
    char* ws = (char*)d_ws;
    size_t off = 0;
    auto take = [&](size_t bytes) -> char* {
        char* p = ws + off;
        off += (bytes + 255) & ~(size_t)255;
        return p;
    };
    float* h      = (float*)take((size_t)N_NODES * DIM * 4);
    float* agg    = (float*)take((size_t)N_NODES * DIM * 4);  // also h2 (aliased)
    ushort_t* y   = (ushort_t*)take((size_t)N_NODES * DIM2 * 2);
    float* pool   = (float*)take((size_t)N_GRAPH * DIM * 4 + (size_t)N_GRAPH * 4);
    float* cnt    = pool + (size_t)N_GRAPH * DIM;
    double* bnsum = (double*)take(DIM * 8 * 2);
    double* bnsq  = bnsum + DIM;
    float* bnmean = (float*)take(DIM * 4 * 2);
    float* bnrstd = bnmean + DIM;
    // packed weight planes
    const size_t W1P = (size_t)NLAYER * NT1 * KB1 * 1024;  // 1,024,000
    const size_t W2P = (size_t)NLAYER * NT2 * KB2 * 1024;  // 1,167,360
    ushort_t* w1hi = (ushort_t*)take(W1P * 2);
    ushort_t* w1lo = (ushort_t*)take(W1P * 2);
    ushort_t* w2hi = (ushort_t*)take(W2P * 2);
    ushort_t* w2lo = (ushort_t*)take(W2P * 2);
    float* h2 = agg;
    (void)ws_size; (void)in_sizes; (void)n_in; (void)out_size;

    const int TB = 256;
    const int gN75 = cdiv((long long)N_NODES * D4, TB);
    const int gE75 = cdiv((long long)N_EDGES * D4, TB);

    // pack weights once per call
    k_pack_w<<<cdiv((long long)W1P, TB), TB, 0, stream>>>(W1, w1hi, w1lo, DIM, DIM2, KB1, NT1, (int)W1P);
    k_pack_w<<<cdiv((long long)W2P, TB), TB, 0, stream>>>(W2, w2hi, w2lo, DIM2, DIM, KB2, NT2, (int)W2P);

    auto run_gnn = [&](const int* xp, const int* eip, const int* eap, const int* batp,
                       float* out_pred, float* out_graph, float* out_node) {
        k_embed_init<<<gN75, TB, 0, stream>>>(xp, xemb1, xemb2, h);
        for (int l = 0; l < NLAYER; ++l) {
            const float* ee1l = eemb1 + (size_t)l * 6 * DIM;
            const float* ee2l = eemb2 + (size_t)l * 3 * DIM;
            k_agg_init<<<gN75, TB, 0, stream>>>(h, ee1l + 4 * DIM, ee2l, agg);
            k_edge_scatter<<<gE75, TB, 0, stream>>>(eip, eap, h, ee1l, ee2l, agg);
            // GEMM1: y = relu(agg @ W1[l] + b1[l])   [50000x300]x[300x600]
            k_gemm_mfma<true, true, ushort_t>
                <<<dim3(NT1, MT_TILES), TB, 0, stream>>>(
                    agg, w1hi + (size_t)l * NT1 * KB1 * 1024, w1lo + (size_t)l * NT1 * KB1 * 1024,
                    b1 + (size_t)l * DIM2, y, N_NODES, DIM, DIM2, 10, KB1);
            // GEMM2: h2 = y @ W2[l] + b2[l]          [50000x600]x[600x300]
            k_gemm_mfma<false, false, float>
                <<<dim3(NT2, MT_TILES), TB, 0, stream>>>(
                    y, w2hi + (size_t)l * NT2 * KB2 * 1024, w2lo + (size_t)l * NT2 * KB2 * 1024,
                    b2 + (size_t)l * DIM, h2, N_NODES, DIM2, DIM, 19, KB2);
            hipMemsetAsync(bnsum, 0, DIM * 8 * 2, stream);
            k_bn_reduce<<<cdiv(N_NODES, 128), TB, 0, stream>>>(h2, bnsum, bnsq);
            k_bn_finalize<<<1, 512, 0, stream>>>(bnsum, bnsq, bnmean, bnrstd);
            if (l < NLAYER - 1)
                k_bn_apply<true, false><<<gN75, TB, 0, stream>>>(
                    h2, bnmean, bnrstd, gamma + (size_t)l * DIM, beta + (size_t)l * DIM, h, nullptr);
            else
                k_bn_apply<false, true><<<gN75, TB, 0, stream>>>(
                    h2, bnmean, bnrstd, gamma + (size_t)l * DIM, beta + (size_t)l * DIM, h, out_node);
        }
        hipMemsetAsync(pool, 0, (size_t)N_GRAPH * DIM * 4 + (size_t)N_GRAPH * 4, stream);
        k_pool_cnt<<<cdiv(N_NODES, TB), TB, 0, stream>>>(batp, cnt);
        k_pool_sum<<<gN75, TB, 0, stream>>>(h, batp, pool);
        k_pool_div<<<cdiv((long long)N_GRAPH * D4, TB), TB, 0, stream>>>(pool, cnt, out_graph);
        k_pred<<<cdiv((long long)N_GRAPH * NTASK, TB), TB, 0, stream>>>(pool, predW, predb, out_pred);
    };

    const size_t GT = (size_t)N_GRAPH * NTASK;       // 20000
    const size_t GD = (size_t)N_GRAPH * DIM;         // 600000
    const size_t ND = (size_t)N_NODES * DIM;         // 15000000
    run_gnn(x, ei, ea, bat, out, out + GT, out + GT + GD);
    run_gnn(x1, ei1, ea1, bat1, out + GT + GD + ND, out + 2 * GT + GD + ND, out + 2 * GT + 2 * GD + ND);
}

// Round 5
// 4293.114 us; speedup vs baseline: 3.7745x; 1.9320x over previous
//
#include <hip/hip_runtime.h>
#include <hip/hip_bf16.h>

typedef unsigned short ushort_t;
typedef short v8s __attribute__((ext_vector_type(8)));
typedef unsigned short v8u __attribute__((ext_vector_type(8)));
typedef float v4f __attribute__((ext_vector_type(4)));

#define N_NODES 50000
#define N_EDGES 100000
#define N_GRAPH 2000
#define DIM     300
#define DIM2    600
#define NLAYER  5
#define NTASK   10
#define D4      75   // DIM/4

// GEMM1: K=300 -> Ksteps=10, KB=40; N=600 -> NT=5 (Npad 640)
// GEMM2: K=600 -> Ksteps=19, KB=76; N=300 -> NT=3 (Npad 384)
#define KB1 40
#define NT1 5
#define KB2 76
#define NT2 3
#define MT_TILES 391  // ceil(50000/128)

static __device__ __forceinline__ float bf2f(ushort_t b) {
    unsigned int u = ((unsigned int)b) << 16;
    float f;
    __builtin_memcpy(&f, &u, 4);
    return f;
}
static __device__ __forceinline__ ushort_t f2bf(float f) {
    unsigned int u;
    __builtin_memcpy(&u, &f, 4);
    unsigned int lsb = (u >> 16) & 1u;
    u += 0x7fffu + lsb;
    return (ushort_t)(u >> 16);
}
// split fp32 into truncated-hi bf16 + residual-lo bf16 (hi + lo ~= f to ~2^-17)
static __device__ __forceinline__ void split2(float f, ushort_t& h, ushort_t& l) {
    unsigned int u;
    __builtin_memcpy(&u, &f, 4);
    h = (ushort_t)(u >> 16);
    unsigned int um = u & 0xFFFF0000u;
    float hf;
    __builtin_memcpy(&hf, &um, 4);
    float lf = f - hf;
    unsigned int ul;
    __builtin_memcpy(&ul, &lf, 4);
    l = (ushort_t)(ul >> 16);
}

// h[n,d] = xemb1[x[n,0],d] + xemb2[x[n,1],d]   (fp32 embeddings)
__global__ void k_embed_init(const int* __restrict__ x,
                             const float* __restrict__ xe1,
                             const float* __restrict__ xe2,
                             float* __restrict__ h) {
    int tid = blockIdx.x * blockDim.x + threadIdx.x;
    if (tid >= N_NODES * D4) return;
    int node = tid / D4;
    int d0 = (tid % D4) * 4;
    int i0 = x[node * 2 + 0];
    int i1 = x[node * 2 + 1];
    float4 a = *(const float4*)(xe1 + (size_t)i0 * DIM + d0);
    float4 b = *(const float4*)(xe2 + (size_t)i1 * DIM + d0);
    float4 o;
    o.x = a.x + b.x; o.y = a.y + b.y; o.z = a.z + b.z; o.w = a.w + b.w;
    *(float4*)(h + (size_t)node * DIM + d0) = o;
}

// ---------------- CSR build (once per launch; edges constant across layers) ----------------
__global__ void k_deg(const int* __restrict__ ei, int* __restrict__ deg) {
    int e = blockIdx.x * blockDim.x + threadIdx.x;
    if (e >= N_EDGES) return;
    atomicAdd(&deg[ei[N_EDGES + e]], 1);
}

// per-block exclusive scan of 256-chunks + block totals
__global__ void k_scan1(const int* __restrict__ deg, int* __restrict__ excl,
                        int* __restrict__ blksum) {
    __shared__ int s[256];
    int i = blockIdx.x * 256 + threadIdx.x;
    int v = (i < N_NODES) ? deg[i] : 0;
    s[threadIdx.x] = v;
    __syncthreads();
#pragma unroll
    for (int o = 1; o < 256; o <<= 1) {
        int t = (threadIdx.x >= o) ? s[threadIdx.x - o] : 0;
        __syncthreads();
        s[threadIdx.x] += t;
        __syncthreads();
    }
    if (i < N_NODES) excl[i] = s[threadIdx.x] - v;
    if (threadIdx.x == 255) blksum[blockIdx.x] = s[255];
}

__global__ void k_scan2(int* __restrict__ blksum, int* __restrict__ blkoff, int nblk) {
    __shared__ int s[256];
    int v = (threadIdx.x < nblk) ? blksum[threadIdx.x] : 0;
    s[threadIdx.x] = v;
    __syncthreads();
#pragma unroll
    for (int o = 1; o < 256; o <<= 1) {
        int t = (threadIdx.x >= o) ? s[threadIdx.x - o] : 0;
        __syncthreads();
        s[threadIdx.x] += t;
        __syncthreads();
    }
    if (threadIdx.x < nblk) blkoff[threadIdx.x] = s[threadIdx.x] - v;
}

__global__ void k_scan3(const int* __restrict__ excl, const int* __restrict__ blkoff,
                        int* __restrict__ rowptr, int* __restrict__ fillptr) {
    int i = blockIdx.x * blockDim.x + threadIdx.x;
    if (i > N_NODES) return;
    int v = (i < N_NODES) ? (excl[i] + blkoff[i >> 8]) : N_EDGES;
    rowptr[i] = v;
    if (i < N_NODES) fillptr[i] = v;
}

__global__ void k_fill(const int* __restrict__ ei, const int* __restrict__ ea,
                       int* __restrict__ fillptr,
                       int* __restrict__ csrc, int* __restrict__ cea) {
    int e = blockIdx.x * blockDim.x + threadIdx.x;
    if (e >= N_EDGES) return;
    int dst = ei[N_EDGES + e];
    int pos = atomicAdd(&fillptr[dst], 1);
    csrc[pos] = ei[e];
    cea[pos] = (ea[2 * e + 0] << 16) | ea[2 * e + 1];
}

// agg[n,:] = h[n,:] + selfloop + sum_{e->n} (h[src]+ee1[a0]+ee2[a1]);   no atomics
__global__ void k_gather_agg(const int* __restrict__ rowptr,
                             const int* __restrict__ csrc,
                             const int* __restrict__ cea,
                             const float* __restrict__ h,
                             const float* __restrict__ ee1,
                             const float* __restrict__ ee2,
                             const float* __restrict__ ee1sl,
                             const float* __restrict__ ee2sl,
                             float* __restrict__ agg) {
    int tid = blockIdx.x * blockDim.x + threadIdx.x;
    if (tid >= N_NODES * D4) return;
    int node = tid / D4;
    int d0 = (tid % D4) * 4;
    float4 a = *(const float4*)(h + (size_t)node * DIM + d0);
    float4 e1 = *(const float4*)(ee1sl + d0);
    float4 e2 = *(const float4*)(ee2sl + d0);
    a.x += e1.x + e2.x; a.y += e1.y + e2.y; a.z += e1.z + e2.z; a.w += e1.w + e2.w;
    int p0 = rowptr[node], p1 = rowptr[node + 1];
    for (int p = p0; p < p1; ++p) {
        int src = csrc[p];
        int pk = cea[p];
        int a0 = pk >> 16, a1 = pk & 0xFFFF;
        float4 hv = *(const float4*)(h + (size_t)src * DIM + d0);
        float4 f1 = *(const float4*)(ee1 + (size_t)a0 * DIM + d0);
        float4 f2 = *(const float4*)(ee2 + (size_t)a1 * DIM + d0);
        a.x += hv.x + f1.x + f2.x;
        a.y += hv.y + f1.y + f2.y;
        a.z += hv.z + f1.z + f2.z;
        a.w += hv.w + f1.w + f2.w;
    }
    *(float4*)(agg + (size_t)node * DIM + d0) = a;
}

// Pack weights W [L][K][N] fp32 -> hi/lo bf16 planes, layout [l][nt][kb][n(128)][j(8)]
__global__ void k_pack_w(const float* __restrict__ W,
                         ushort_t* __restrict__ hi,
                         ushort_t* __restrict__ lo,
                         int K, int N, int KBv, int NTv, int total) {
    int idx = blockIdx.x * blockDim.x + threadIdx.x;
    if (idx >= total) return;
    int j = idx & 7;
    int n = (idx >> 3) & 127;
    int tmp = idx >> 10;
    int kb = tmp % KBv; tmp /= KBv;
    int nt = tmp % NTv;
    int l = tmp / NTv;
    int k = kb * 8 + j;
    int ng = nt * 128 + n;
    float v = 0.f;
    if (k < K && ng < N) v = W[((size_t)l * K + k) * N + ng];
    ushort_t h, lw;
    split2(v, h, lw);
    hi[idx] = h;
    lo[idx] = lw;
}

// MFMA split-precision GEMM: C[M,N] = act(A[M,Ka] @ W[Ka,N] + bias)
template <bool RELU, bool SPLITA, typename OT>
__global__ __launch_bounds__(256) void k_gemm_mfma(
        const void* __restrict__ Av,
        const ushort_t* __restrict__ Bhi,
        const ushort_t* __restrict__ Blo,
        const float* __restrict__ bias,
        OT* __restrict__ C,
        int M, int Ka, int N, int Ksteps, int KBv) {
    alignas(16) __shared__ ushort_t sAhi[4096];            // [kb4][m128][j8]
    alignas(16) __shared__ ushort_t sAlo[SPLITA ? 4096 : 16];
    alignas(16) __shared__ ushort_t sBhi[4096];            // [kb4][n128][j8]
    alignas(16) __shared__ ushort_t sBlo[4096];

    const int nt = blockIdx.x;
    const int mt = blockIdx.y;
    const int t = threadIdx.x;

    const int w = t >> 6;
    const int lane = t & 63;
    const int wm = w >> 1;
    const int wn = w & 1;
    const int quad = lane >> 4;
    const int lr = lane & 15;

    v4f acc[4][4];
#pragma unroll
    for (int i = 0; i < 4; ++i)
#pragma unroll
        for (int j = 0; j < 4; ++j) acc[i][j] = (v4f){0.f, 0.f, 0.f, 0.f};

    const int sm = t >> 1;
    const int shalf = t & 1;
    const size_t srow = (size_t)mt * 128 + sm;
    const bool rv = srow < (size_t)M;

    for (int ks = 0; ks < Ksteps; ++ks) {
        const int kk = ks * 32;
        if (SPLITA) {
            const float* ap = (const float*)Av + srow * (size_t)Ka;
#pragma unroll
            for (int c = 0; c < 2; ++c) {
                v8u h8, l8;
#pragma unroll
                for (int q2 = 0; q2 < 2; ++q2) {
                    int ko = shalf * 16 + c * 8 + q2 * 4;
                    float4 v = {0.f, 0.f, 0.f, 0.f};
                    if (rv && (kk + ko) < Ka) v = *(const float4*)(ap + kk + ko);
                    const float* vp = &v.x;
#pragma unroll
                    for (int i = 0; i < 4; ++i) {
                        ushort_t hh, ll;
                        split2(vp[i], hh, ll);
                        h8[q2 * 4 + i] = hh;
                        l8[q2 * 4 + i] = ll;
                    }
                }
                int kb = shalf * 2 + c;
                *(v8u*)&sAhi[kb * 1024 + sm * 8] = h8;
                *(v8u*)&sAlo[kb * 1024 + sm * 8] = l8;
            }
        } else {
            const ushort_t* ap = (const ushort_t*)Av + srow * (size_t)Ka;
#pragma unroll
            for (int c = 0; c < 2; ++c) {
                int ko = shalf * 16 + c * 8;
                v8u v = {0, 0, 0, 0, 0, 0, 0, 0};
                if (rv && (kk + ko) < Ka) v = *(const v8u*)(ap + kk + ko);
                *(v8u*)&sAhi[(shalf * 2 + c) * 1024 + sm * 8] = v;
            }
        }
        {
            const size_t base = ((size_t)nt * KBv + ks * 4) * 1024;
            const ushort_t* bh = Bhi + base;
            const ushort_t* bl = Blo + base;
#pragma unroll
            for (int p = 0; p < 2; ++p) {
                int o = p * 2048 + t * 8;
                *(v8u*)&sBhi[o] = *(const v8u*)(bh + o);
                *(v8u*)&sBlo[o] = *(const v8u*)(bl + o);
            }
        }
        __syncthreads();
        v8s a_hi[4], a_lo[4], b_hi[4], b_lo[4];
#pragma unroll
        for (int s = 0; s < 4; ++s) {
            a_hi[s] = *(const v8s*)&sAhi[quad * 1024 + (wm * 64 + s * 16 + lr) * 8];
            if (SPLITA)
                a_lo[s] = *(const v8s*)&sAlo[quad * 1024 + (wm * 64 + s * 16 + lr) * 8];
            b_hi[s] = *(const v8s*)&sBhi[quad * 1024 + (wn * 64 + s * 16 + lr) * 8];
            b_lo[s] = *(const v8s*)&sBlo[quad * 1024 + (wn * 64 + s * 16 + lr) * 8];
        }
#pragma unroll
        for (int si = 0; si < 4; ++si) {
#pragma unroll
            for (int sj = 0; sj < 4; ++sj) {
                acc[si][sj] = __builtin_amdgcn_mfma_f32_16x16x32_bf16(
                    a_hi[si], b_hi[sj], acc[si][sj], 0, 0, 0);
                acc[si][sj] = __builtin_amdgcn_mfma_f32_16x16x32_bf16(
                    a_hi[si], b_lo[sj], acc[si][sj], 0, 0, 0);
                if (SPLITA)
                    acc[si][sj] = __builtin_amdgcn_mfma_f32_16x16x32_bf16(
                        a_lo[si], b_hi[sj], acc[si][sj], 0, 0, 0);
            }
        }
        __syncthreads();
    }

#pragma unroll
    for (int sj = 0; sj < 4; ++sj) {
        int col = nt * 128 + wn * 64 + sj * 16 + lr;
        if (col >= N) continue;
        float bv = bias[col];
#pragma unroll
        for (int si = 0; si < 4; ++si) {
#pragma unroll
            for (int r = 0; r < 4; ++r) {
                size_t row = (size_t)mt * 128 + wm * 64 + si * 16 + quad * 4 + r;
                if (row >= (size_t)M) continue;
                float v = acc[si][sj][r] + bv;
                if (RELU) v = fmaxf(v, 0.f);
                if (sizeof(OT) == 2)
                    ((ushort_t*)C)[row * N + col] = f2bf(v);
                else
                    ((float*)C)[row * N + col] = v;
            }
        }
    }
}

// per-column partial sums of h2 into double accumulators
__global__ void k_bn_reduce(const float* __restrict__ h2,
                            double* __restrict__ sum,
                            double* __restrict__ sumsq) {
    const int ROWS = 128;
    int r0 = blockIdx.x * ROWS;
    int rend = r0 + ROWS;
    if (rend > N_NODES) rend = N_NODES;
    for (int d = threadIdx.x; d < DIM; d += 256) {
        float s = 0.f, q = 0.f;
        for (int r = r0; r < rend; ++r) {
            float v = h2[(size_t)r * DIM + d];
            s += v;
            q += v * v;
        }
        atomicAdd(&sum[d], (double)s);
        atomicAdd(&sumsq[d], (double)q);
    }
}

__global__ void k_bn_finalize(const double* __restrict__ sum,
                              const double* __restrict__ sumsq,
                              float* __restrict__ mean,
                              float* __restrict__ rstd) {
    int d = threadIdx.x;
    if (d >= DIM) return;
    double mu = sum[d] / (double)N_NODES;
    double var = sumsq[d] / (double)N_NODES - mu * mu;
    if (var < 0.0) var = 0.0;
    mean[d] = (float)mu;
    rstd[d] = (float)(1.0 / sqrt(var + 1e-5));
}

template <bool RELU, bool WOUT>
__global__ void k_bn_apply(const float* __restrict__ h2,
                           const float* __restrict__ mean,
                           const float* __restrict__ rstd,
                           const float* __restrict__ gamma,
                           const float* __restrict__ beta,
                           float* __restrict__ h,
                           float* __restrict__ nodeout) {
    int tid = blockIdx.x * blockDim.x + threadIdx.x;
    if (tid >= N_NODES * D4) return;
    int node = tid / D4;
    int d0 = (tid % D4) * 4;
    float4 v = *(const float4*)(h2 + (size_t)node * DIM + d0);
    float o[4] = {v.x, v.y, v.z, v.w};
    float4 r;
    float* rp = &r.x;
#pragma unroll
    for (int i = 0; i < 4; ++i) {
        int d = d0 + i;
        float u = (o[i] - mean[d]) * rstd[d] * gamma[d] + beta[d];
        if (RELU) u = fmaxf(u, 0.f);
        rp[i] = u;
    }
    *(float4*)(h + (size_t)node * DIM + d0) = r;
    if (WOUT) *(float4*)(nodeout + (size_t)node * DIM + d0) = r;
}

__global__ void k_pool_cnt(const int* __restrict__ batch, float* __restrict__ cnt) {
    int tid = blockIdx.x * blockDim.x + threadIdx.x;
    if (tid >= N_NODES) return;
    atomicAdd(&cnt[batch[tid]], 1.0f);
}

__global__ void k_pool_sum(const float* __restrict__ h,
                           const int* __restrict__ batch,
                           float* __restrict__ pool) {
    int tid = blockIdx.x * blockDim.x + threadIdx.x;
    if (tid >= N_NODES * D4) return;
    int node = tid / D4;
    int d0 = (tid % D4) * 4;
    int g = batch[node];
    float4 v = *(const float4*)(h + (size_t)node * DIM + d0);
    float* dp = pool + (size_t)g * DIM + d0;
    atomicAdd(dp + 0, v.x);
    atomicAdd(dp + 1, v.y);
    atomicAdd(dp + 2, v.z);
    atomicAdd(dp + 3, v.w);
}

__global__ void k_pool_div(float* __restrict__ pool,
                           const float* __restrict__ cnt,
                           float* __restrict__ gout) {
    int tid = blockIdx.x * blockDim.x + threadIdx.x;
    if (tid >= N_GRAPH * D4) return;
    int g = tid / D4;
    int d0 = (tid % D4) * 4;
    float c = fmaxf(cnt[g], 1.0f);
    float* pp = pool + (size_t)g * DIM + d0;
    float4 r;
    r.x = pp[0] / c; r.y = pp[1] / c; r.z = pp[2] / c; r.w = pp[3] / c;
    *(float4*)pp = r;
    *(float4*)(gout + (size_t)g * DIM + d0) = r;
}

__global__ void k_pred(const float* __restrict__ pool,
                       const float* __restrict__ predW,
                       const float* __restrict__ predb,
                       float* __restrict__ out) {
    int tid = blockIdx.x * blockDim.x + threadIdx.x;
    if (tid >= N_GRAPH * NTASK) return;
    int g = tid / NTASK;
    int tt = tid % NTASK;
    float s = predb[tt];
    const float* pr = pool + (size_t)g * DIM;
    for (int k = 0; k < DIM; ++k) s += pr[k] * predW[k * NTASK + tt];
    out[(size_t)g * NTASK + tt] = s;
}

static inline int cdiv(long long a, long long b) { return (int)((a + b - 1) / b); }

extern "C" void kernel_launch(void* const* d_in, const int* in_sizes, int n_in,
                              void* d_out, int out_size, void* d_ws, size_t ws_size,
                              hipStream_t stream) {
    const int* x    = (const int*)d_in[0];
    const int* ei   = (const int*)d_in[1];
    const int* ea   = (const int*)d_in[2];
    const int* bat  = (const int*)d_in[3];
    const int* x1   = (const int*)d_in[4];
    const int* ei1  = (const int*)d_in[5];
    const int* ea1  = (const int*)d_in[6];
    const int* bat1 = (const int*)d_in[7];
    const float* xemb1 = (const float*)d_in[8];
    const float* xemb2 = (const float*)d_in[9];
    const float* eemb1 = (const float*)d_in[10];
    const float* eemb2 = (const float*)d_in[11];
    const float* W1    = (const float*)d_in[12];
    const float* b1    = (const float*)d_in[13];
    const float* W2    = (const float*)d_in[14];
    const float* b2    = (const float*)d_in[15];
    const float* gamma = (const float*)d_in[16];
    const float* beta  = (const float*)d_in[17];
    const float* predW = (const float*)d_in[18];
    const float* predb = (const float*)d_in[19];
    float* out = (float*)d_out;  // reference outputs are float32

    // workspace layout (~195 MB)
    char* ws = (char*)d_ws;
    size_t off = 0;
    auto take = [&](size_t bytes) -> char* {
        char* p = ws + off;
        off += (bytes + 255) & ~(size_t)255;
        return p;
    };
    float* h      = (float*)take((size_t)N_NODES * DIM * 4);
    float* agg    = (float*)take((size_t)N_NODES * DIM * 4);  // also h2 (aliased)
    ushort_t* y   = (ushort_t*)take((size_t)N_NODES * DIM2 * 2);
    float* pool   = (float*)take((size_t)N_GRAPH * DIM * 4 + (size_t)N_GRAPH * 4);
    float* cnt    = pool + (size_t)N_GRAPH * DIM;
    double* bnsum = (double*)take(DIM * 8 * 2);
    double* bnsq  = bnsum + DIM;
    float* bnmean = (float*)take(DIM * 4 * 2);
    float* bnrstd = bnmean + DIM;
    // packed weight planes
    const size_t W1P = (size_t)NLAYER * NT1 * KB1 * 1024;  // 1,024,000
    const size_t W2P = (size_t)NLAYER * NT2 * KB2 * 1024;  // 1,167,360
    ushort_t* w1hi = (ushort_t*)take(W1P * 2);
    ushort_t* w1lo = (ushort_t*)take(W1P * 2);
    ushort_t* w2hi = (ushort_t*)take(W2P * 2);
    ushort_t* w2lo = (ushort_t*)take(W2P * 2);
    // CSR buffers (built once per launch)
    int* deg     = (int*)take(N_NODES * 4);
    int* excl    = (int*)take(N_NODES * 4);
    int* blksum  = (int*)take(256 * 4);
    int* blkoff  = (int*)take(256 * 4);
    int* fillptr = (int*)take(N_NODES * 4);
    int* rowptr0 = (int*)take((N_NODES + 1) * 4);
    int* csrc0   = (int*)take(N_EDGES * 4);
    int* cea0    = (int*)take(N_EDGES * 4);
    int* rowptr1 = (int*)take((N_NODES + 1) * 4);
    int* csrc1   = (int*)take(N_EDGES * 4);
    int* cea1    = (int*)take(N_EDGES * 4);
    float* h2 = agg;
    (void)ws_size; (void)in_sizes; (void)n_in; (void)out_size;

    const int TB = 256;
    const int gN75 = cdiv((long long)N_NODES * D4, TB);
    const int gE   = cdiv(N_EDGES, TB);
    const int gScan = cdiv(N_NODES, TB);          // 196
    const int gScan3 = cdiv(N_NODES + 1, TB);

    // pack weights once per call
    k_pack_w<<<cdiv((long long)W1P, TB), TB, 0, stream>>>(W1, w1hi, w1lo, DIM, DIM2, KB1, NT1, (int)W1P);
    k_pack_w<<<cdiv((long long)W2P, TB), TB, 0, stream>>>(W2, w2hi, w2lo, DIM2, DIM, KB2, NT2, (int)W2P);

    // build CSR once per graph
    auto build_csr = [&](const int* eip, const int* eap, int* rowptr, int* csrc, int* cea) {
        hipMemsetAsync(deg, 0, N_NODES * 4, stream);
        k_deg<<<gE, TB, 0, stream>>>(eip, deg);
        k_scan1<<<gScan, TB, 0, stream>>>(deg, excl, blksum);
        k_scan2<<<1, 256, 0, stream>>>(blksum, blkoff, gScan);
        k_scan3<<<gScan3, TB, 0, stream>>>(excl, blkoff, rowptr, fillptr);
        k_fill<<<gE, TB, 0, stream>>>(eip, eap, fillptr, csrc, cea);
    };
    build_csr(ei, ea, rowptr0, csrc0, cea0);
    build_csr(ei1, ea1, rowptr1, csrc1, cea1);

    auto run_gnn = [&](const int* xp, const int* batp,
                       const int* rowptr, const int* csrc, const int* cea,
                       float* out_pred, float* out_graph, float* out_node) {
        k_embed_init<<<gN75, TB, 0, stream>>>(xp, xemb1, xemb2, h);
        for (int l = 0; l < NLAYER; ++l) {
            const float* ee1l = eemb1 + (size_t)l * 6 * DIM;
            const float* ee2l = eemb2 + (size_t)l * 3 * DIM;
            k_gather_agg<<<gN75, TB, 0, stream>>>(rowptr, csrc, cea, h,
                                                  ee1l, ee2l, ee1l + 4 * DIM, ee2l, agg);
            // GEMM1: y = relu(agg @ W1[l] + b1[l])   [50000x300]x[300x600]
            k_gemm_mfma<true, true, ushort_t>
                <<<dim3(NT1, MT_TILES), TB, 0, stream>>>(
                    agg, w1hi + (size_t)l * NT1 * KB1 * 1024, w1lo + (size_t)l * NT1 * KB1 * 1024,
                    b1 + (size_t)l * DIM2, y, N_NODES, DIM, DIM2, 10, KB1);
            // GEMM2: h2 = y @ W2[l] + b2[l]          [50000x600]x[600x300]
            k_gemm_mfma<false, false, float>
                <<<dim3(NT2, MT_TILES), TB, 0, stream>>>(
                    y, w2hi + (size_t)l * NT2 * KB2 * 1024, w2lo + (size_t)l * NT2 * KB2 * 1024,
                    b2 + (size_t)l * DIM, h2, N_NODES, DIM2, DIM, 19, KB2);
            hipMemsetAsync(bnsum, 0, DIM * 8 * 2, stream);
            k_bn_reduce<<<cdiv(N_NODES, 128), TB, 0, stream>>>(h2, bnsum, bnsq);
            k_bn_finalize<<<1, 512, 0, stream>>>(bnsum, bnsq, bnmean, bnrstd);
            if (l < NLAYER - 1)
                k_bn_apply<true, false><<<gN75, TB, 0, stream>>>(
                    h2, bnmean, bnrstd, gamma + (size_t)l * DIM, beta + (size_t)l * DIM, h, nullptr);
            else
                k_bn_apply<false, true><<<gN75, TB, 0, stream>>>(
                    h2, bnmean, bnrstd, gamma + (size_t)l * DIM, beta + (size_t)l * DIM, h, out_node);
        }
        hipMemsetAsync(pool, 0, (size_t)N_GRAPH * DIM * 4 + (size_t)N_GRAPH * 4, stream);
        k_pool_cnt<<<cdiv(N_NODES, TB), TB, 0, stream>>>(batp, cnt);
        k_pool_sum<<<gN75, TB, 0, stream>>>(h, batp, pool);
        k_pool_div<<<cdiv((long long)N_GRAPH * D4, TB), TB, 0, stream>>>(pool, cnt, out_graph);
        k_pred<<<cdiv((long long)N_GRAPH * NTASK, TB), TB, 0, stream>>>(pool, predW, predb, out_pred);
    };

    const size_t GT = (size_t)N_GRAPH * NTASK;       // 20000
    const size_t GD = (size_t)N_GRAPH * DIM;         // 600000
    const size_t ND = (size_t)N_NODES * DIM;         // 15000000
    run_gnn(x, bat, rowptr0, csrc0, cea0, out, out + GT, out + GT + GD);
    run_gnn(x1, bat1, rowptr1, csrc1, cea1,
            out + GT + GD + ND, out + 2 * GT + GD + ND, out + 2 * GT + 2 * GD + ND);
}